// Round 8
// baseline (231.161 us; speedup 1.0000x reference)
//
#include <hip/hip_runtime.h>

// RecurrentGCN (DCRNN cell, K=1) — MFMA version, round 8.
// R7 post-mortem: coalesced weight prologue CONFIRMED the TA-pipe theory
// (92->65us, loop body unchanged). Remaining top counter: VALUBusy 43%.
// Recount: R7's glue (copied from R4) uses IEEE f32 DIVISION in sigmoid x16
// and tanh x8 -> ~10 instr each = ~250 VALU/tile (half the VALU budget).
// R6 with v_rcp measured VALUBusy 21% - corroborates.
// This round:
//  (1) v_rcp_f32 for both divides (1 ulp; invisible at bf16).
//  (2) exp2 weight-folding: W_z,W_r,b_z,b_r scaled by -log2(e); W_h,b_h by
//      2*log2(e). Activations use exp2f() = bare v_exp_f32 (v_exp IS 2^x).
//  (3) grid 1024 (7.6 tiles/wave): halves prologue instances, single cohort.

#define N_NODES 500000
#define IN_DIM  16
#define HID     32
#define OUT_DIM 8
#define XH      48         // IN_DIM + HID
#define NTILES  31250      // N_NODES / 16 (exact)
#define WROW    72         // sW row stride in bf16 (64 k-pad + 8)

typedef unsigned int u32;
typedef unsigned short u16;
typedef __attribute__((ext_vector_type(8))) short bf16x8;  // 8 bf16 = 4 VGPR
typedef __attribute__((ext_vector_type(4))) float f32x4;   // MFMA 16x16 acc

static __device__ __forceinline__ float bfbits(u32 hi){ union{u32 x; float f;} t; t.x=hi; return t.f; }
static __device__ __forceinline__ float bflo(u32 u){ return bfbits(u<<16); }
static __device__ __forceinline__ float bfhi(u32 u){ return bfbits(u & 0xffff0000u); }
static __device__ __forceinline__ float bf2f(u16 s){ return bfbits(((u32)s)<<16); }
static __device__ __forceinline__ float u2f(u32 u){ union{u32 x; float f;} t; t.x=u; return t.f; }
static __device__ __forceinline__ u32 f2u(float f){ union{float f;u32 x;} t; t.f=f; return t.x; }
// packed f32->bf16 RNE, 1 instr (lo = a, hi = b)
static __device__ __forceinline__ u32 cvtpk(float a, float b){
    u32 r; asm("v_cvt_pk_bf16_f32 %0, %1, %2" : "=v"(r) : "v"(a), "v"(b)); return r;
}
static __device__ __forceinline__ u16 f2bf(float f){
    union{float f;u32 x;} t; t.f=f; u32 x=t.x;
    return (u16)((x + 0x7fffu + ((x>>16)&1u)) >> 16);      // RNE
}
static __device__ __forceinline__ float rcp_(float x){
    float r; asm("v_rcp_f32 %0, %1" : "=v"(r) : "v"(x)); return r;
}
// z-gate from PRE-SCALED preact a' = -log2(e)*a: sigmoid(a) = rcp(1+2^a')
// saturates: a'->+inf => 2^a'=inf => rcp=0; a'->-inf => rcp(1)=1.
static __device__ __forceinline__ float sigm2(float ap){
    return rcp_(1.f + exp2f(ap));
}
// tanh from PRE-SCALED preact a' = 2*log2(e)*a: e=2^(-|a'|), t=(1-e)/(1+e)
static __device__ __forceinline__ float tanh2(float ap){
    float e = exp2f(-fabsf(ap));
    return __builtin_copysignf((1.f - e) * rcp_(1.f + e), ap);
}

#define LFENCE() asm volatile("s_waitcnt lgkmcnt(0)" ::: "memory")
#define MFMA16(a,b,c) __builtin_amdgcn_mfma_f32_16x16x32_bf16(a,b,c,0,0,0)

static __device__ __forceinline__ float ldf(const void* p, int i, bool F32){
    return F32 ? ((const float*)p)[i] : bf2f(((const u16*)p)[i]);
}
// stage tile: [16 rows][64 bf16 cols] = 128 B rows; XOR swizzle on 16B chunks
static __device__ __forceinline__ char* stgp(char* base, int row, int off){
    return base + row*128 + (off ^ ((row & 7) << 4));
}

#define NLOG2E  (-1.44269504f)     // -log2(e): scale for W_z, W_r, b_z, b_r
#define P2LOG2E ( 2.88539008f)     // 2*log2(e): scale for W_h, b_h

__global__ __launch_bounds__(256)
void rgcn_kernel(const void* __restrict__ xp_,   // [N,16]
                 const void* __restrict__ hp_,   // [N,32]
                 const void* __restrict__ wz_, const void* __restrict__ bz_,
                 const void* __restrict__ wr_, const void* __restrict__ br_,
                 const void* __restrict__ wh_, const void* __restrict__ bh_,
                 const void* __restrict__ wl_, const void* __restrict__ bl_,
                 void* __restrict__ dout_)       // out [N,8] ++ h_new [N,32]
{
    __shared__ u16 sW[3][32*WROW];     // combined+scaled bf16 weights [col][k+pad]
    __shared__ u16 sStage[4][16*64];   // per-wave bf16 [x|h] -> [x|hr] -> [relu(hn)|hr]
    __shared__ int sF32;

    const int tid = threadIdx.x;

    // ---- dtype detection (wave-parallel: f32 iff any low-half is insane bf16)
    if (tid < 64) {
        const u32* xw = (const u32*)xp_;
        int bad = 0;
#pragma unroll
        for (int q = 0; q < 2; q++) {
            float lo = bflo(xw[tid*2 + q]);
            if (!(fabsf(lo) <= 1e6f)) bad = 1;
        }
        unsigned long long m = __ballot(bad);
        if (tid == 0) sF32 = (m != 0ull) ? 1 : 0;
    }
    __syncthreads();
    const bool F32 = (sF32 != 0);

    // ---- COALESCED weight prep (R7): linear reads of w ([2][48][32]),
    // sum halves + exp2 pre-scale in regs, transpose on the LDS-write side:
    // sW[m][c][k] = bf16( (w[0][k][c]+w[1][k][c]) * scale[m] ).
    {
        const void* wsrc[3] = { wz_, wr_, wh_ };
        const float wscl[3] = { NLOG2E, NLOG2E, P2LOG2E };
#pragma unroll
        for (int m = 0; m < 3; m++) {
            u16* dst = sW[m];
            const float sc = wscl[m];
            if (F32) {
                const float* w = (const float*)wsrc[m];
                for (int o = tid; o < 384; o += 256) {          // 384 float4 = 1536 f32
                    float4 a = *(const float4*)(w + 4*o);        // w[0] half, [k][c]
                    float4 b = *(const float4*)(w + 1536 + 4*o); // w[1] half
                    int base = 4*o;
                    int k = base >> 5, c = base & 31;            // 4 consecutive c, same k
                    dst[(c+0)*WROW + k] = f2bf((a.x + b.x) * sc);
                    dst[(c+1)*WROW + k] = f2bf((a.y + b.y) * sc);
                    dst[(c+2)*WROW + k] = f2bf((a.z + b.z) * sc);
                    dst[(c+3)*WROW + k] = f2bf((a.w + b.w) * sc);
                }
            } else {
                const u16* w = (const u16*)wsrc[m];
                for (int o = tid; o < 192; o += 256) {           // 192 uint4 = 1536 u16
                    uint4 a = *(const uint4*)(w + 8*o);
                    uint4 b = *(const uint4*)(w + 1536 + 8*o);
                    int base = 8*o;
                    int k = base >> 5, c = base & 31;            // 8 consecutive c, same k
                    const u32 aw[4] = {a.x, a.y, a.z, a.w};
                    const u32 bw[4] = {b.x, b.y, b.z, b.w};
#pragma unroll
                    for (int q = 0; q < 4; q++) {
                        dst[(c+2*q+0)*WROW + k] = f2bf((bflo(aw[q]) + bflo(bw[q])) * sc);
                        dst[(c+2*q+1)*WROW + k] = f2bf((bfhi(aw[q]) + bfhi(bw[q])) * sc);
                    }
                }
            }
        }
        // zero the k-pad rows (k = 48..63) once, coalesced over threads
        for (int o = tid; o < 32*16; o += 256) {
            int c = o >> 4, k = 48 + (o & 15);
            sW[0][c*WROW + k] = 0; sW[1][c*WROW + k] = 0; sW[2][c*WROW + k] = 0;
        }
    }
    __syncthreads();

    const int lane = tid & 63, wv = tid >> 6;
    const int c16 = lane & 15, g = lane >> 4;     // MFMA frag coords
    const int row4 = lane >> 2, q4 = lane & 3;    // staging coords
    char* stage = (char*)sStage[wv];

    // ---- loop-invariant LDS pointers
    char* pXw = stgp(stage, row4, q4*8);            // x stage write (8B)
    char* pHw = stgp(stage, row4, 32 + q4*16);      // h stage write (16B)
    char* pA0 = stgp(stage, c16, 16*g);             // A frag k 0..31 (also relu(hn))
    char* pA1 = stgp(stage, c16, 64 + 16*g);        // A frag k 32..63
    char* pPairH[4]; char* pPairR[4];
#pragma unroll
    for (int rr = 0; rr < 4; rr++) {
        int nl = g*4 + rr;
        pPairH[rr] = stgp(stage, nl, 32 + 4*c16);   // h/hr pair (cols 2c16,2c16+1)
        pPairR[rr] = stgp(stage, nl, 4*c16);        // relu(hn) pair
    }

    // zero K-pad (stage bytes 96..127 per row = cols 48..63), once
    {
        uint2 z2; z2.x = 0u; z2.y = 0u;
        *(uint2*)stgp(stage, row4, 96 + q4*8) = z2;
    }

    // ---- biases, PRE-SCALED to match folded weights (cols 2*c16+tt)
    float bzv[2], brv[2], bhv[2];
#pragma unroll
    for (int tt = 0; tt < 2; tt++) {
        bzv[tt] = NLOG2E  * ldf(bz_, 2*c16 + tt, F32);
        brv[tt] = NLOG2E  * ldf(br_, 2*c16 + tt, F32);
        bhv[tt] = P2LOG2E * ldf(bh_, 2*c16 + tt, F32);
    }
    float blv = (c16 < OUT_DIM) ? ldf(bl_, c16, F32) : 0.f;

    // ---- B-fragments from LDS weight images (12 ds_read_b128 per wave)
    // B layout: lane (c16,g) covers TRUE col 2*c16+tt, k = kt*32 + g*8 + e.
    bf16x8 Bz[2][2], Br[2][2], Bh[2][2], Bl;
#pragma unroll
    for (int kt = 0; kt < 2; kt++) {
#pragma unroll
        for (int tt = 0; tt < 2; tt++) {
            int boff = (2*c16 + tt)*(WROW*2) + (kt*32 + g*8)*2;
            Bz[kt][tt] = *(const bf16x8*)((const char*)sW[0] + boff);
            Br[kt][tt] = *(const bf16x8*)((const char*)sW[1] + boff);
            Bh[kt][tt] = *(const bf16x8*)((const char*)sW[2] + boff);
        }
    }
    {
        union { u16 us[8]; bf16x8 v; } ul;
#pragma unroll
        for (int e = 0; e < 8; e++) {
            int k = g*8 + e;
            float v = (c16 < OUT_DIM) ? ldf(wl_, k*OUT_DIM + c16, F32) : 0.f;
            ul.us[e] = f2bf(v);
        }
        Bl = ul.v;
    }

    // global output bases
    float* outF = (float*)dout_;
    float* hnF  = outF + (size_t)N_NODES * OUT_DIM;
    u16*   outB = (u16*)dout_;
    u16*   hnB  = outB + (size_t)N_NODES * OUT_DIM;

    const int wid = blockIdx.x*4 + wv;
    const int nw  = gridDim.x*4;

    // ---- prefetch registers (next tile's x/h, raw bits in float4 lanes)
    float4 pfx, pfh0, pfh1;
#define PLOAD(TT) do { \
        size_t nbp = (size_t)(TT) * 16; \
        if (F32) { \
            const float* xb = (const float*)xp_ + nbp*IN_DIM; \
            pfx  = *(const float4*)(xb + row4*IN_DIM + q4*4); \
            const float* hb = (const float*)hp_ + nbp*HID; \
            pfh0 = *(const float4*)(hb + row4*HID + q4*8); \
            pfh1 = *(const float4*)(hb + row4*HID + q4*8 + 4); \
        } else { \
            const u16* xb = (const u16*)xp_ + nbp*IN_DIM; \
            uint2 xv = *(const uint2*)(xb + row4*IN_DIM + q4*4); \
            pfx.x = u2f(xv.x); pfx.y = u2f(xv.y); \
            const u16* hb = (const u16*)hp_ + nbp*HID; \
            uint4 hv = *(const uint4*)(hb + row4*HID + q4*8); \
            pfh0.x = u2f(hv.x); pfh0.y = u2f(hv.y); pfh0.z = u2f(hv.z); pfh0.w = u2f(hv.w); \
        } \
    } while (0)

    if (wid < NTILES) PLOAD(wid);

    for (int t = wid; t < NTILES; t += nw) {
        const size_t nb = (size_t)t * 16;

        // ---- stage current tile from prefetched regs (bf16 pack + ds_write)
        if (F32) {
            uint2 xp2; xp2.x = cvtpk(pfx.x, pfx.y); xp2.y = cvtpk(pfx.z, pfx.w);
            *(uint2*)pXw = xp2;
            uint4 hp4; hp4.x = cvtpk(pfh0.x, pfh0.y); hp4.y = cvtpk(pfh0.z, pfh0.w);
            hp4.z = cvtpk(pfh1.x, pfh1.y); hp4.w = cvtpk(pfh1.z, pfh1.w);
            *(uint4*)pHw = hp4;
        } else {
            uint2 xp2; xp2.x = f2u(pfx.x); xp2.y = f2u(pfx.y);
            *(uint2*)pXw = xp2;
            uint4 hp4; hp4.x = f2u(pfh0.x); hp4.y = f2u(pfh0.y);
            hp4.z = f2u(pfh0.z); hp4.w = f2u(pfh0.w);
            *(uint4*)pHw = hp4;
        }

        // ---- issue NEXT tile's global loads now; consumed next iteration
        {
            int tn = t + nw;
            if (tn < NTILES) PLOAD(tn);
        }
        LFENCE();

        // ---- A1 = [x | h] fragments + h pairs (read-before-overwrite)
        bf16x8 a0 = *(const bf16x8*)pA0;
        bf16x8 a1 = *(const bf16x8*)pA1;
        u32 hwp[4];
#pragma unroll
        for (int rr = 0; rr < 4; rr++) hwp[rr] = *(const u32*)pPairH[rr];

        // ---- GEMM1: z and r pre-scaled preacts (permuted cols), bias-seeded
        f32x4 accZ[2], accR[2];
#pragma unroll
        for (int tt = 0; tt < 2; tt++) {
            f32x4 az; az[0]=bzv[tt]; az[1]=bzv[tt]; az[2]=bzv[tt]; az[3]=bzv[tt];
            az = MFMA16(a0, Bz[0][tt], az);
            az = MFMA16(a1, Bz[1][tt], az);
            accZ[tt] = az;
            f32x4 ar; ar[0]=brv[tt]; ar[1]=brv[tt]; ar[2]=brv[tt]; ar[3]=brv[tt];
            ar = MFMA16(a0, Br[0][tt], ar);
            ar = MFMA16(a1, Br[1][tt], ar);
            accR[tt] = ar;
        }

        // ---- glue 1: z/r via exp2+rcp; hr pair -> one cvt_pk + one b32 write
        float z0a[4], z1a[4], hv0[4], hv1[4];
#pragma unroll
        for (int rr = 0; rr < 4; rr++) {
            float h0 = bflo(hwp[rr]), h1 = bfhi(hwp[rr]);
            hv0[rr] = h0; hv1[rr] = h1;
            float z0 = sigm2(accZ[0][rr]), z1 = sigm2(accZ[1][rr]);
            z0a[rr] = z0; z1a[rr] = z1;
            float r0 = sigm2(accR[0][rr]), r1 = sigm2(accR[1][rr]);
            *(u32*)pPairH[rr] = cvtpk(h0*r0, h1*r1);
        }
        LFENCE();

        // ---- GEMMh: A2 = [x | h*r] (x half still valid)
        bf16x8 b0 = *(const bf16x8*)pA0;
        bf16x8 b1 = *(const bf16x8*)pA1;
        f32x4 accH[2];
#pragma unroll
        for (int tt = 0; tt < 2; tt++) {
            f32x4 ah; ah[0]=bhv[tt]; ah[1]=bhv[tt]; ah[2]=bhv[tt]; ah[3]=bhv[tt];
            ah = MFMA16(b0, Bh[0][tt], ah);
            ah = MFMA16(b1, Bh[1][tt], ah);
            accH[tt] = ah;
        }

        // ---- glue 2: hn = ht + z*(h-ht); relu(hn)->stage; hn->global DIRECT
#pragma unroll
        for (int rr = 0; rr < 4; rr++) {
            int nl = g*4 + rr;
            float t0 = tanh2(accH[0][rr]), t1 = tanh2(accH[1][rr]);
            float n0 = t0 + z0a[rr]*(hv0[rr] - t0);
            float n1 = t1 + z1a[rr]*(hv1[rr] - t1);
            *(u32*)pPairR[rr] = cvtpk(fmaxf(n0, 0.f), fmaxf(n1, 0.f));
            if (F32) {
                float2 st; st.x = n0; st.y = n1;
                *(float2*)(hnF + (nb + nl)*HID + 2*c16) = st;
            } else {
                *(u32*)(hnB + (nb + nl)*HID + 2*c16) = cvtpk(n0, n1);
            }
        }
        LFENCE();

        // ---- GEMMout: relu(hn) [16,32] @ [32,8]; store direct from acc
        bf16x8 a3 = *(const bf16x8*)pA0;
        f32x4 accO; accO[0]=blv; accO[1]=blv; accO[2]=blv; accO[3]=blv;
        accO = MFMA16(a3, Bl, accO);
        if (c16 < OUT_DIM) {
            if (F32) {
#pragma unroll
                for (int rr = 0; rr < 4; rr++)
                    outF[(nb + g*4 + rr)*OUT_DIM + c16] = accO[rr];
            } else {
#pragma unroll
                for (int rr = 0; rr < 4; rr++)
                    outB[(nb + g*4 + rr)*OUT_DIM + c16] = (u16)(cvtpk(accO[rr], accO[rr]) & 0xffffu);
            }
        }
    }
#undef PLOAD
}

extern "C" void kernel_launch(void* const* d_in, const int* in_sizes, int n_in,
                              void* d_out, int out_size, void* d_ws, size_t ws_size,
                              hipStream_t stream) {
    // setup_inputs() order:
    // 0 x, 1 edge_index(unused), 2 edge_weight(unused), 3 h,
    // 4 w_z, 5 b_z, 6 w_r, 7 b_r, 8 w_h, 9 b_h, 10 w_lin, 11 b_lin
    const int block = 256;     // 4 waves; each wave owns independent 16-node tiles
    const int grid  = 1024;    // 4096 waves (~7.6 tiles each): prologue amortized
    rgcn_kernel<<<grid, block, 0, stream>>>(
        d_in[0], d_in[3], d_in[4], d_in[5], d_in[6], d_in[7],
        d_in[8], d_in[9], d_in[10], d_in[11], d_out);
}